// Round 1
// 73.286 us; speedup vs baseline: 1.0323x; 1.0323x over previous
//
#include <hip/hip_runtime.h>
#include <math.h>

// Problem constants: B=4, N=512, M=512, ZD=128, YD=2, XD=1
#define B_  4
#define N_  512
#define M_  512
#define ZD_ 128
#define YD_ 2
#define MB_ 8                 // m-values per block

#define LOG2E_HALF 0.72134752044f   // 0.5*log2(e)

// Fused decoder. Math (uniform length-scale fast path):
//   out[b,m,y] = sum_n (sum_c W[y,c] z[b,n,c]) * 2^(a2 (x_m - t_n)^2) + bias[y]
// Valid because sigma is channel-uniform => kernel weight is c-independent.
// Uniformity is checked at runtime per-block; non-uniform sigma takes the
// exact per-channel fallback (data-dependent, deterministic across replays).
//
// Parallelism: grid (M_/MB_=64, B_) = 256 blocks (1 per CU), 256 threads.
// Thread (tid>>5) = local m (0..7), (tid&31) = n-slice. Each slice covers
// n = slice + 32*i (interleaved -> consecutive LDS addrs, conflict-free).
// Final reduction: 5-step shfl_xor inside each 32-lane half; lanes 0/32 of
// each wave own one m and write the float2 directly (no LDS, no barrier).
// zw[n][y] = z[b,n,:].W[y,:] is recomputed per block (64 blocks share b);
// redundant FLOPs are free (latency-bound), z[b] re-reads hit L2 (256 KB).
__global__ __launch_bounds__(256)
void decoder_fused(const float* __restrict__ t,
                   const float* __restrict__ z,
                   const float* __restrict__ x,
                   const float* __restrict__ sigma,
                   const float* __restrict__ W,
                   const float* __restrict__ bias,
                   float* __restrict__ out)
{
    __shared__ float ts[N_];            // 2 KB: t row for this b
    __shared__ float zw0[N_];           // 2 KB: sum_c W[0,c] z[b,n,c]
    __shared__ float zw1[N_];           // 2 KB: sum_c W[1,c] z[b,n,c]
    __shared__ float Wl[YD_ * ZD_];     // 1 KB
    __shared__ float a2s;               // uniform coefficient
    __shared__ int   oks;               // uniformity flag

    const int b   = blockIdx.y;
    const int m0  = blockIdx.x * MB_;
    const int tid = threadIdx.x;

    if (tid == 0) oks = 1;
    if (tid < (YD_ * ZD_) / 4)
        ((float4*)Wl)[tid] = ((const float4*)W)[tid];
    __syncthreads();

    // Uniformity check + uniform coefficient (threads 0..127 over channels).
    if (tid < ZD_) {
        const float sc  = __expf(sigma[tid]);
        const float a2  = -LOG2E_HALF / (sc * sc);
        const float sc0 = __expf(sigma[0]);
        const float a20 = -LOG2E_HALF / (sc0 * sc0);
        if (a2 != a20) oks = 0;         // benign race: all writers store 0
        if (tid == 0) a2s = a20;
    }

    // Stage t and compute zw[n][y] = z[b,n,:] . W[y,:] (2 n-rows per thread).
    for (int n = tid; n < N_; n += 256) {
        ts[n] = t[(size_t)b * N_ + n];  // XD=1
        const float4* zr = (const float4*)(z + ((size_t)b * N_ + n) * ZD_);
        float s0 = 0.f, s1 = 0.f;
        #pragma unroll 8
        for (int k = 0; k < ZD_ / 4; ++k) {
            const float4 zv = zr[k];
            const float4 w0 = ((const float4*)Wl)[k];
            const float4 w1 = ((const float4*)Wl)[ZD_ / 4 + k];
            s0 = fmaf(zv.x, w0.x, fmaf(zv.y, w0.y, fmaf(zv.z, w0.z, fmaf(zv.w, w0.w, s0))));
            s1 = fmaf(zv.x, w1.x, fmaf(zv.y, w1.y, fmaf(zv.z, w1.z, fmaf(zv.w, w1.w, s1))));
        }
        zw0[n] = s0;
        zw1[n] = s1;
    }
    __syncthreads();                    // covers zw/ts writes + oks/a2s

    const int   ml    = tid >> 5;       // local m: 0..7
    const int   slice = tid & 31;       // n-slice: 0..31
    const int   m     = m0 + ml;
    const float xm    = x[(size_t)b * M_ + m];   // XD=1

    float s0 = 0.f, s1 = 0.f;
    if (oks) {
        // Fast path: one exp per (n, m). 16 iters; LDS addrs consecutive
        // across the 32 lanes of each half-wave -> conflict-free.
        const float a2 = a2s;
        #pragma unroll
        for (int i = 0; i < N_ / 32; ++i) {
            const int   n = slice + 32 * i;
            const float d = xm - ts[n];
            const float e = __builtin_amdgcn_exp2f(a2 * d * d);
            s0 = fmaf(zw0[n], e, s0);
            s1 = fmaf(zw1[n], e, s1);
        }
    } else {
        // Exact general path: per-channel scales (recompute a2_c from sigma).
        for (int i = 0; i < N_ / 32; ++i) {
            const int   n  = slice + 32 * i;
            const float d  = xm - ts[n];
            const float d2 = d * d;
            const float* zr = z + ((size_t)b * N_ + n) * ZD_;
            for (int c = 0; c < ZD_; ++c) {
                const float sc = __expf(sigma[c]);
                const float ac = -LOG2E_HALF / (sc * sc);
                const float e  = __builtin_amdgcn_exp2f(ac * d2);
                const float p  = zr[c] * e;
                s0 = fmaf(Wl[c],       p, s0);
                s1 = fmaf(Wl[ZD_ + c], p, s1);
            }
        }
    }

    // Reduce the 32 slice-partials within each 32-lane half (xor<32 stays
    // inside the half). Lane 0 holds m=2w, lane 32 holds m=2w+1.
    #pragma unroll
    for (int d = 16; d >= 1; d >>= 1) {
        s0 += __shfl_xor(s0, d, 64);
        s1 += __shfl_xor(s1, d, 64);
    }

    if ((tid & 31) == 0) {
        const int mm = m0 + (tid >> 5);
        *(float2*)(out + ((size_t)b * M_ + mm) * YD_)
            = make_float2(bias[0] + s0, bias[1] + s1);
    }
}

extern "C" void kernel_launch(void* const* d_in, const int* in_sizes, int n_in,
                              void* d_out, int out_size, void* d_ws, size_t ws_size,
                              hipStream_t stream) {
    const float* t     = (const float*)d_in[0];
    const float* z     = (const float*)d_in[1];
    const float* x     = (const float*)d_in[2];
    const float* sigma = (const float*)d_in[3];
    const float* W     = (const float*)d_in[4];
    const float* bias  = (const float*)d_in[5];
    float* out = (float*)d_out;

    decoder_fused<<<dim3(M_ / MB_, B_), dim3(256), 0, stream>>>(
        t, z, x, sigma, W, bias, out);
}

// Round 2
// 71.725 us; speedup vs baseline: 1.0547x; 1.0218x over previous
//
#include <hip/hip_runtime.h>
#include <math.h>

// Problem constants: B=4, N=512, M=512, ZD=128, YD=2, XD=1
#define B_  4
#define N_  512
#define M_  512
#define ZD_ 128
#define YD_ 2
#define MB_ 8                 // m-values per block (one per wave)

#define LOG2E_HALF 0.72134752044f   // 0.5*log2(e)

// Fused decoder. Math (uniform length-scale fast path):
//   out[b,m,y] = sum_n (sum_c W[y,c] z[b,n,c]) * 2^(a2 (x_m - t_n)^2) + bias[y]
// Valid because sigma is channel-uniform => kernel weight is c-independent.
// Uniformity is checked at runtime per-block; non-uniform sigma takes the
// exact per-channel fallback (data-dependent, deterministic across replays).
//
// Parallelism: grid (M_/MB_=64, B_) = 256 blocks (1 per CU), 512 threads
// = 8 waves/CU = 2 waves/SIMD (TLP for load-latency hiding).
// Staging: one z-row per thread (512 rows / 512 threads) -- 32 float4 L2
// loads + 256 FMAs critical path (half of the 256-thread version).
// Main loop: wave w owns m = m0+w; lane = n-slice (n = lane + 64*i,
// consecutive LDS addrs -> 2 lanes/bank = conflict-free). 8 iters.
// Reduction: 6-step shfl_xor across the full wave; lane 0 writes float2.
// zw[n][y] = z[b,n,:].W[y,:] is recomputed per block (64 blocks share b);
// redundant FLOPs are free (latency-bound), z[b] re-reads hit L2 (256 KB).
__global__ __launch_bounds__(512)
void decoder_fused(const float* __restrict__ t,
                   const float* __restrict__ z,
                   const float* __restrict__ x,
                   const float* __restrict__ sigma,
                   const float* __restrict__ W,
                   const float* __restrict__ bias,
                   float* __restrict__ out)
{
    __shared__ float ts[N_];            // 2 KB: t row for this b
    __shared__ float zw0[N_];           // 2 KB: sum_c W[0,c] z[b,n,c]
    __shared__ float zw1[N_];           // 2 KB: sum_c W[1,c] z[b,n,c]
    __shared__ float Wl[YD_ * ZD_];     // 1 KB
    __shared__ float a2s;               // uniform coefficient
    __shared__ int   oks;               // uniformity flag

    const int b   = blockIdx.y;
    const int m0  = blockIdx.x * MB_;
    const int tid = threadIdx.x;

    if (tid == 0) oks = 1;
    if (tid < (YD_ * ZD_) / 4)
        ((float4*)Wl)[tid] = ((const float4*)W)[tid];
    __syncthreads();

    // Uniformity check + uniform coefficient (threads 0..127 over channels).
    if (tid < ZD_) {
        const float sc  = __expf(sigma[tid]);
        const float a2  = -LOG2E_HALF / (sc * sc);
        const float sc0 = __expf(sigma[0]);
        const float a20 = -LOG2E_HALF / (sc0 * sc0);
        if (a2 != a20) oks = 0;         // benign race: all writers store 0
        if (tid == 0) a2s = a20;
    }

    // Stage t and compute zw[n][y] = z[b,n,:] . W[y,:] (1 n-row per thread).
    {
        const int n = tid;              // N_ == blockDim.x == 512
        ts[n] = t[(size_t)b * N_ + n];  // XD=1
        const float4* zr = (const float4*)(z + ((size_t)b * N_ + n) * ZD_);
        float s0 = 0.f, s1 = 0.f;
        #pragma unroll 8
        for (int k = 0; k < ZD_ / 4; ++k) {
            const float4 zv = zr[k];
            const float4 w0 = ((const float4*)Wl)[k];
            const float4 w1 = ((const float4*)Wl)[ZD_ / 4 + k];
            s0 = fmaf(zv.x, w0.x, fmaf(zv.y, w0.y, fmaf(zv.z, w0.z, fmaf(zv.w, w0.w, s0))));
            s1 = fmaf(zv.x, w1.x, fmaf(zv.y, w1.y, fmaf(zv.z, w1.z, fmaf(zv.w, w1.w, s1))));
        }
        zw0[n] = s0;
        zw1[n] = s1;
    }
    __syncthreads();                    // covers zw/ts writes + oks/a2s

    const int   w    = tid >> 6;        // wave = local m: 0..7
    const int   lane = tid & 63;        // n-slice: 0..63
    const int   m    = m0 + w;
    const float xm   = x[(size_t)b * M_ + m];   // XD=1

    float s0 = 0.f, s1 = 0.f;
    if (oks) {
        // Fast path: one exp per (n, m). 8 iters; LDS addrs consecutive
        // across the 64 lanes -> 2 lanes/bank (free).
        const float a2 = a2s;
        #pragma unroll
        for (int i = 0; i < N_ / 64; ++i) {
            const int   n = lane + 64 * i;
            const float d = xm - ts[n];
            const float e = __builtin_amdgcn_exp2f(a2 * d * d);
            s0 = fmaf(zw0[n], e, s0);
            s1 = fmaf(zw1[n], e, s1);
        }
    } else {
        // Exact general path: per-channel scales (recompute a2_c from sigma).
        for (int i = 0; i < N_ / 64; ++i) {
            const int   n  = lane + 64 * i;
            const float d  = xm - ts[n];
            const float d2 = d * d;
            const float* zr = z + ((size_t)b * N_ + n) * ZD_;
            for (int c = 0; c < ZD_; ++c) {
                const float sc = __expf(sigma[c]);
                const float ac = -LOG2E_HALF / (sc * sc);
                const float e  = __builtin_amdgcn_exp2f(ac * d2);
                const float p  = zr[c] * e;
                s0 = fmaf(Wl[c],       p, s0);
                s1 = fmaf(Wl[ZD_ + c], p, s1);
            }
        }
    }

    // Reduce the 64 slice-partials across the wave.
    #pragma unroll
    for (int d = 32; d >= 1; d >>= 1) {
        s0 += __shfl_xor(s0, d, 64);
        s1 += __shfl_xor(s1, d, 64);
    }

    if (lane == 0) {
        *(float2*)(out + ((size_t)b * M_ + m) * YD_)
            = make_float2(bias[0] + s0, bias[1] + s1);
    }
}

extern "C" void kernel_launch(void* const* d_in, const int* in_sizes, int n_in,
                              void* d_out, int out_size, void* d_ws, size_t ws_size,
                              hipStream_t stream) {
    const float* t     = (const float*)d_in[0];
    const float* z     = (const float*)d_in[1];
    const float* x     = (const float*)d_in[2];
    const float* sigma = (const float*)d_in[3];
    const float* W     = (const float*)d_in[4];
    const float* bias  = (const float*)d_in[5];
    float* out = (float*)d_out;

    decoder_fused<<<dim3(M_ / MB_, B_), dim3(512), 0, stream>>>(
        t, z, x, sigma, W, bias, out);
}